// Round 1
// baseline (2565.702 us; speedup 1.0000x reference)
//
#include <hip/hip_runtime.h>

#define K256 __launch_bounds__(256)

constexpr int B = 128;
constexpr int NM = 100000, EM = 400000;
constexpr int NP = 200000, EP = 3200000;
constexpr int DM = 78, DPK = 54, DP2 = 108;

// ---------- CSR build ----------
__global__ void K256 k_count(const int* __restrict__ dst, int* __restrict__ deg, int E) {
  int e = blockIdx.x * 256 + threadIdx.x;
  if (e < E) atomicAdd(&deg[dst[e]], 1);
}

__global__ void k_scan1(const int* __restrict__ deg, int* __restrict__ incl,
                        int* __restrict__ bsum, int N) {
  __shared__ int s[1024];
  int i = blockIdx.x * 1024 + threadIdx.x;
  int v = (i < N) ? deg[i] : 0;
  s[threadIdx.x] = v;
  __syncthreads();
  for (int off = 1; off < 1024; off <<= 1) {
    int t = (threadIdx.x >= off) ? s[threadIdx.x - off] : 0;
    __syncthreads();
    s[threadIdx.x] += t;
    __syncthreads();
  }
  if (i < N) incl[i] = s[threadIdx.x];
  if (threadIdx.x == 1023) bsum[blockIdx.x] = s[1023];
}

__global__ void k_scan2(int* __restrict__ bsum, int nb) {
  __shared__ int s[256];
  int v = (threadIdx.x < (unsigned)nb) ? bsum[threadIdx.x] : 0;
  s[threadIdx.x] = v;
  __syncthreads();
  for (int off = 1; off < 256; off <<= 1) {
    int t = (threadIdx.x >= off) ? s[threadIdx.x - off] : 0;
    __syncthreads();
    s[threadIdx.x] += t;
    __syncthreads();
  }
  if (threadIdx.x < (unsigned)nb) bsum[threadIdx.x] = s[threadIdx.x] - v;  // exclusive
}

__global__ void K256 k_scan3(const int* __restrict__ incl, const int* __restrict__ deg,
                             const int* __restrict__ bsum, int* __restrict__ starts,
                             int* __restrict__ cur, int N) {
  int i = blockIdx.x * 256 + threadIdx.x;
  if (i < N) {
    int v = incl[i] - deg[i] + bsum[i >> 10];
    starts[i] = v;
    cur[i] = v;
  }
}

__global__ void K256 k_fill(const int* __restrict__ src, const int* __restrict__ dst,
                            int* __restrict__ cur, int* __restrict__ csr, int E) {
  int e = blockIdx.x * 256 + threadIdx.x;
  if (e < E) {
    int p = atomicAdd(&cur[dst[e]], 1);
    csr[p] = src[e];
  }
}

// ---------- gather aggregation: wave per node, lanes = features ----------
template <int D, bool MEAN>
__global__ void K256 k_gather(const float* __restrict__ x, const int* __restrict__ starts,
                              const int* __restrict__ deg, const int* __restrict__ csr,
                              float* __restrict__ out, int N) {
  int wid = (blockIdx.x * 256 + threadIdx.x) >> 6;
  int lane = threadIdx.x & 63;
  if (wid >= N) return;
  int s = starts[wid], d = deg[wid];
  constexpr int R = (D + 63) / 64;
  float acc[R];
#pragma unroll
  for (int r = 0; r < R; r++) acc[r] = 0.f;
  const int* cp = csr + s;
  for (int j = 0; j < d; j++) {
    const float* row = x + (size_t)cp[j] * D;
#pragma unroll
    for (int r = 0; r < R; r++) {
      int f = lane + 64 * r;
      if (f < D) acc[r] += row[f];
    }
  }
  float inv = MEAN ? 1.f / fmaxf((float)d, 1.f) : 1.f;
  float* op = out + (size_t)wid * D;
#pragma unroll
  for (int r = 0; r < R; r++) {
    int f = lane + 64 * r;
    if (f < D) op[f] = acc[r] * inv;
  }
}

// ---------- batched pooling accumulate (mol), LDS accumulator ----------
template <int D>
__global__ void K256 k_pool(const float* __restrict__ x, const int* __restrict__ batch,
                            float* __restrict__ pooled, float* __restrict__ cnt, float coef,
                            int N, int do_count) {
  __shared__ float sp[B * D];
  __shared__ float sc[B];
  for (int t = threadIdx.x; t < B * D; t += 256) sp[t] = 0.f;
  for (int t = threadIdx.x; t < B; t += 256) sc[t] = 0.f;
  __syncthreads();
  int chunk = (N + gridDim.x - 1) / gridDim.x;
  int i0 = blockIdx.x * chunk, i1 = min(N, i0 + chunk);
  for (int t = i0 * D + (int)threadIdx.x; t < i1 * D; t += 256) {
    int i = t / D, f = t - i * D;
    atomicAdd(&sp[batch[i] * D + f], coef * x[t]);
  }
  if (do_count)
    for (int i = i0 + (int)threadIdx.x; i < i1; i += 256) atomicAdd(&sc[batch[i]], 1.f);
  __syncthreads();
  for (int t = threadIdx.x; t < B * D; t += 256) {
    float v = sp[t];
    if (v != 0.f) atomicAdd(&pooled[t], v);
  }
  if (do_count)
    for (int t = threadIdx.x; t < B; t += 256) {
      float v = sc[t];
      if (v != 0.f) atomicAdd(&cnt[t], v);
    }
}

// ---------- SAGE node update: out = relu(aggm @ Wl^T + bl + x @ Wr^T) ----------
template <int K, int O>
__global__ void K256 k_sage_node(const float* __restrict__ x, const float* __restrict__ agg,
                                 const float* __restrict__ Wl, const float* __restrict__ bl,
                                 const float* __restrict__ Wr, float* __restrict__ out, int N) {
  int i = blockIdx.x * 256 + threadIdx.x;
  if (i >= N) return;
  float xr[K], am[K];
  const float* xp = x + (size_t)i * K;
  const float* ap = agg + (size_t)i * K;
#pragma unroll
  for (int k = 0; k < K; k++) {
    xr[k] = xp[k];
    am[k] = ap[k];
  }
  float* op = out + (size_t)i * O;
#pragma unroll 1
  for (int o = 0; o < O; o += 6) {
    float a0 = bl[o + 0], a1 = bl[o + 1], a2 = bl[o + 2];
    float a3 = bl[o + 3], a4 = bl[o + 4], a5 = bl[o + 5];
#pragma unroll
    for (int k = 0; k < K; k++) {
      float xv = xr[k], av = am[k];
      a0 += av * Wl[(o + 0) * K + k] + xv * Wr[(o + 0) * K + k];
      a1 += av * Wl[(o + 1) * K + k] + xv * Wr[(o + 1) * K + k];
      a2 += av * Wl[(o + 2) * K + k] + xv * Wr[(o + 2) * K + k];
      a3 += av * Wl[(o + 3) * K + k] + xv * Wr[(o + 3) * K + k];
      a4 += av * Wl[(o + 4) * K + k] + xv * Wr[(o + 4) * K + k];
      a5 += av * Wl[(o + 5) * K + k] + xv * Wr[(o + 5) * K + k];
    }
    op[o + 0] = fmaxf(a0, 0.f);
    op[o + 1] = fmaxf(a1, 0.f);
    op[o + 2] = fmaxf(a2, 0.f);
    op[o + 3] = fmaxf(a3, 0.f);
    op[o + 4] = fmaxf(a4, 0.f);
    op[o + 5] = fmaxf(a5, 0.f);
  }
}

// ---------- conv2 node update fused with segment-mean pooling ----------
__global__ void K256 k_sage2_pool(const float* __restrict__ xt1, const float* __restrict__ agg,
                                  const float* __restrict__ Wl, const float* __restrict__ bl,
                                  const float* __restrict__ Wr, const int* __restrict__ batch,
                                  float* __restrict__ pooled, float* __restrict__ cnt, int N) {
  __shared__ float sp[B * DP2];
  __shared__ float sc[B];
  for (int t = threadIdx.x; t < B * DP2; t += 256) sp[t] = 0.f;
  for (int t = threadIdx.x; t < B; t += 256) sc[t] = 0.f;
  __syncthreads();
  int chunk = (N + gridDim.x - 1) / gridDim.x;
  int i0 = blockIdx.x * chunk, i1 = min(N, i0 + chunk);
  for (int i = i0 + (int)threadIdx.x; i < i1; i += 256) {
    float xr[DPK], am[DPK];
    const float* xp = xt1 + (size_t)i * DPK;
    const float* ap = agg + (size_t)i * DPK;
#pragma unroll
    for (int k = 0; k < DPK; k++) {
      xr[k] = xp[k];
      am[k] = ap[k];
    }
    int b = batch[i];
    atomicAdd(&sc[b], 1.f);
    float* spb = sp + b * DP2;
#pragma unroll 1
    for (int o = 0; o < DP2; o += 6) {
      float a0 = bl[o + 0], a1 = bl[o + 1], a2 = bl[o + 2];
      float a3 = bl[o + 3], a4 = bl[o + 4], a5 = bl[o + 5];
#pragma unroll
      for (int k = 0; k < DPK; k++) {
        float xv = xr[k], av = am[k];
        a0 += av * Wl[(o + 0) * DPK + k] + xv * Wr[(o + 0) * DPK + k];
        a1 += av * Wl[(o + 1) * DPK + k] + xv * Wr[(o + 1) * DPK + k];
        a2 += av * Wl[(o + 2) * DPK + k] + xv * Wr[(o + 2) * DPK + k];
        a3 += av * Wl[(o + 3) * DPK + k] + xv * Wr[(o + 3) * DPK + k];
        a4 += av * Wl[(o + 4) * DPK + k] + xv * Wr[(o + 4) * DPK + k];
        a5 += av * Wl[(o + 5) * DPK + k] + xv * Wr[(o + 5) * DPK + k];
      }
      atomicAdd(&spb[o + 0], fmaxf(a0, 0.f));
      atomicAdd(&spb[o + 1], fmaxf(a1, 0.f));
      atomicAdd(&spb[o + 2], fmaxf(a2, 0.f));
      atomicAdd(&spb[o + 3], fmaxf(a3, 0.f));
      atomicAdd(&spb[o + 4], fmaxf(a4, 0.f));
      atomicAdd(&spb[o + 5], fmaxf(a5, 0.f));
    }
  }
  __syncthreads();
  for (int t = threadIdx.x; t < B * DP2; t += 256) {
    float v = sp[t];
    if (v != 0.f) atomicAdd(&pooled[t], v);
  }
  for (int t = threadIdx.x; t < B; t += 256) {
    float v = sc[t];
    if (v != 0.f) atomicAdd(&cnt[t], v);
  }
}

// ---------- branch head MLP: mean -> 256 relu -> DOUT (linear) ----------
template <int DIN, int DOUT>
__global__ void K256 k_head(const float* __restrict__ pooled, const float* __restrict__ cnt,
                            const float* __restrict__ W1, const float* __restrict__ b1,
                            const float* __restrict__ W2, const float* __restrict__ b2,
                            float* __restrict__ outv) {
  __shared__ float sx[DIN];
  __shared__ float sh[256];
  int b = blockIdx.x, tid = threadIdx.x;
  float inv = 1.f / fmaxf(cnt[b], 1.f);
  for (int f = tid; f < DIN; f += 256) sx[f] = pooled[b * DIN + f] * inv;
  __syncthreads();
  float acc = b1[tid];
#pragma unroll 2
  for (int k = 0; k < DIN; k++) acc += sx[k] * W1[tid * DIN + k];
  sh[tid] = fmaxf(acc, 0.f);
  __syncthreads();
  if (tid < DOUT) {
    float a = b2[tid];
#pragma unroll 4
    for (int k = 0; k < 256; k++) a += sh[k] * W2[tid * 256 + k];
    outv[b * DOUT + tid] = a;
  }
}

// ---------- final: concat -> 1024 relu -> 512 relu -> 1 ----------
__global__ void K256 k_final(const float* __restrict__ molv, const float* __restrict__ prov,
                             const float* __restrict__ W1, const float* __restrict__ b1,
                             const float* __restrict__ W2, const float* __restrict__ b2,
                             const float* __restrict__ W3, const float* __restrict__ b3,
                             float* __restrict__ out) {
  __shared__ float sx[256];
  __shared__ float sh1[1024];
  __shared__ float sh2[512];
  __shared__ float red[4];
  int b = blockIdx.x, tid = threadIdx.x;
  sx[tid] = (tid < 112) ? molv[b * 112 + tid] : prov[b * 144 + (tid - 112)];
  __syncthreads();
  for (int o = tid; o < 1024; o += 256) {
    float a = b1[o];
#pragma unroll 4
    for (int k = 0; k < 256; k++) a += sx[k] * W1[o * 256 + k];
    sh1[o] = fmaxf(a, 0.f);
  }
  __syncthreads();
  for (int o = tid; o < 512; o += 256) {
    float a = b2[o];
#pragma unroll 4
    for (int k = 0; k < 1024; k++) a += sh1[k] * W2[o * 1024 + k];
    sh2[o] = fmaxf(a, 0.f);
  }
  __syncthreads();
  float a = 0.f;
  for (int k = tid; k < 512; k += 256) a += sh2[k] * W3[k];
  for (int off = 32; off > 0; off >>= 1) a += __shfl_down(a, off, 64);
  if ((tid & 63) == 0) red[tid >> 6] = a;
  __syncthreads();
  if (tid == 0) out[b] = red[0] + red[1] + red[2] + red[3] + b3[0];
}

__global__ void k_report(float* out, float v, int n) {
  int i = blockIdx.x * 256 + threadIdx.x;
  if (i < n) out[i] = v;
}

extern "C" void kernel_launch(void* const* d_in, const int* in_sizes, int n_in,
                              void* d_out, int out_size, void* d_ws, size_t ws_size,
                              hipStream_t stream) {
  (void)in_sizes; (void)n_in;
  const float* mol_x = (const float*)d_in[0];
  const int* m_ei = (const int*)d_in[1];
  const int* m_batch = (const int*)d_in[2];
  const float* pro_x = (const float*)d_in[3];
  const int* p_ei = (const int*)d_in[4];
  const int* p_batch = (const int*)d_in[5];
  const float* mol_W1 = (const float*)d_in[6];
  const float* mol_b1 = (const float*)d_in[7];
  const float* mol_W2 = (const float*)d_in[8];
  const float* mol_b2 = (const float*)d_in[9];
  const float* c1_Wl = (const float*)d_in[10];
  const float* c1_bl = (const float*)d_in[11];
  const float* c1_Wr = (const float*)d_in[12];
  const float* c2_Wl = (const float*)d_in[13];
  const float* c2_bl = (const float*)d_in[14];
  const float* c2_Wr = (const float*)d_in[15];
  const float* pro_W1 = (const float*)d_in[16];
  const float* pro_b1 = (const float*)d_in[17];
  const float* pro_W2 = (const float*)d_in[18];
  const float* pro_b2 = (const float*)d_in[19];
  const float* fc1_W = (const float*)d_in[20];
  const float* fc1_b = (const float*)d_in[21];
  const float* fc2_W = (const float*)d_in[22];
  const float* fc2_b = (const float*)d_in[23];
  const float* out_W = (const float*)d_in[24];
  const float* out_b = (const float*)d_in[25];
  float* out = (float*)d_out;
  char* ws = (char*)d_ws;

  const int* m_row = m_ei;       // dst (scatter target of APPNP)
  const int* m_col = m_ei + EM;  // src (gathered)
  const int* p_e0 = p_ei;        // src
  const int* p_e1 = p_ei + EP;   // dst

  auto al = [](size_t x) { return (x + 255) & ~(size_t)255; };

  // pro region (defines union size); mol region overlaps it (phases are sequential)
  size_t o = 0;
  size_t o_pdeg = o;  o += al((size_t)NP * 4);
  size_t o_pincl = o; o += al((size_t)NP * 4);
  size_t o_pstart = o; o += al((size_t)NP * 4);
  size_t o_pcur = o;  o += al((size_t)NP * 4);
  size_t o_pbsum = o; o += al(1024);
  size_t o_pcsr = o;  o += al((size_t)EP * 4);
  size_t o_agg = o;   o += al((size_t)NP * DPK * 4);
  size_t o_xt1 = o;   o += al((size_t)NP * DPK * 4);
  size_t pro_end = o;

  o = 0;
  size_t o_mdeg = o;  o += al((size_t)NM * 4);
  size_t o_mincl = o; o += al((size_t)NM * 4);
  size_t o_mstart = o; o += al((size_t)NM * 4);
  size_t o_mcur = o;  o += al((size_t)NM * 4);
  size_t o_mbsum = o; o += al(1024);
  size_t o_mcsr = o;  o += al((size_t)EM * 4);
  size_t o_hA = o;    o += al((size_t)NM * DM * 4);
  size_t o_hB = o;    o += al((size_t)NM * DM * 4);
  size_t mol_end = o;

  size_t tail = al(pro_end > mol_end ? pro_end : mol_end);
  size_t o_poolM = tail; tail += al((size_t)B * DM * 4);
  size_t o_cntM = tail;  tail += al((size_t)B * 4);
  size_t o_poolP = tail; tail += al((size_t)B * DP2 * 4);
  size_t o_cntP = tail;  tail += al((size_t)B * 4);
  size_t o_molv = tail;  tail += al((size_t)B * 112 * 4);
  size_t o_prov = tail;  tail += al((size_t)B * 144 * 4);

  if (ws_size < tail) {
    // diagnostic: report available ws MB so the failure is identifiable
    k_report<<<1, 256, 0, stream>>>(out, (float)(ws_size >> 20), out_size);
    return;
  }

  int* mdeg = (int*)(ws + o_mdeg);
  int* mincl = (int*)(ws + o_mincl);
  int* mstart = (int*)(ws + o_mstart);
  int* mcur = (int*)(ws + o_mcur);
  int* mbsum = (int*)(ws + o_mbsum);
  int* mcsr = (int*)(ws + o_mcsr);
  float* hA = (float*)(ws + o_hA);
  float* hB = (float*)(ws + o_hB);
  int* pdeg = (int*)(ws + o_pdeg);
  int* pincl = (int*)(ws + o_pincl);
  int* pstart = (int*)(ws + o_pstart);
  int* pcur = (int*)(ws + o_pcur);
  int* pbsum = (int*)(ws + o_pbsum);
  int* pcsr = (int*)(ws + o_pcsr);
  float* agg = (float*)(ws + o_agg);
  float* xt1 = (float*)(ws + o_xt1);
  float* poolM = (float*)(ws + o_poolM);
  float* cntM = (float*)(ws + o_cntM);
  float* poolP = (float*)(ws + o_poolP);
  float* cntP = (float*)(ws + o_cntP);
  float* molv = (float*)(ws + o_molv);
  float* prov = (float*)(ws + o_prov);

  hipMemsetAsync(poolM, 0, (size_t)B * DM * 4, stream);
  hipMemsetAsync(cntM, 0, (size_t)B * 4, stream);
  hipMemsetAsync(poolP, 0, (size_t)B * DP2 * 4, stream);
  hipMemsetAsync(cntP, 0, (size_t)B * 4, stream);

  // ===== MOL branch =====
  hipMemsetAsync(mdeg, 0, (size_t)NM * 4, stream);
  int eb_m = (EM + 255) / 256;
  k_count<<<eb_m, 256, 0, stream>>>(m_row, mdeg, EM);
  int nb_m = (NM + 1023) / 1024;
  k_scan1<<<nb_m, 1024, 0, stream>>>(mdeg, mincl, mbsum, NM);
  k_scan2<<<1, 256, 0, stream>>>(mbsum, nb_m);
  k_scan3<<<(NM + 255) / 256, 256, 0, stream>>>(mincl, mdeg, mbsum, mstart, mcur, NM);
  k_fill<<<eb_m, 256, 0, stream>>>(m_col, m_row, mcur, mcsr, EM);

  int gb_m = (NM * 64 + 255) / 256;
  k_pool<DM><<<256, 256, 0, stream>>>(mol_x, m_batch, poolM, cntM, 0.05f, NM, 1);
  k_gather<DM, false><<<gb_m, 256, 0, stream>>>(mol_x, mstart, mdeg, mcsr, hA, NM);
  k_pool<DM><<<256, 256, 0, stream>>>(hA, m_batch, poolM, cntM, 0.2375f, NM, 0);
  k_gather<DM, false><<<gb_m, 256, 0, stream>>>(hA, mstart, mdeg, mcsr, hB, NM);
  k_pool<DM><<<256, 256, 0, stream>>>(hB, m_batch, poolM, cntM, 0.2375f, NM, 0);
  k_gather<DM, false><<<gb_m, 256, 0, stream>>>(hB, mstart, mdeg, mcsr, hA, NM);
  k_pool<DM><<<256, 256, 0, stream>>>(hA, m_batch, poolM, cntM, 0.2375f, NM, 0);
  k_gather<DM, false><<<gb_m, 256, 0, stream>>>(hA, mstart, mdeg, mcsr, hB, NM);
  k_pool<DM><<<256, 256, 0, stream>>>(hB, m_batch, poolM, cntM, 0.2375f, NM, 0);
  k_head<DM, 112><<<B, 256, 0, stream>>>(poolM, cntM, mol_W1, mol_b1, mol_W2, mol_b2, molv);

  // ===== PRO branch (reuses the mol region) =====
  hipMemsetAsync(pdeg, 0, (size_t)NP * 4, stream);
  int eb_p = (EP + 255) / 256;
  k_count<<<eb_p, 256, 0, stream>>>(p_e1, pdeg, EP);
  int nb_p = (NP + 1023) / 1024;
  k_scan1<<<nb_p, 1024, 0, stream>>>(pdeg, pincl, pbsum, NP);
  k_scan2<<<1, 256, 0, stream>>>(pbsum, nb_p);
  k_scan3<<<(NP + 255) / 256, 256, 0, stream>>>(pincl, pdeg, pbsum, pstart, pcur, NP);
  k_fill<<<eb_p, 256, 0, stream>>>(p_e0, p_e1, pcur, pcsr, EP);

  int gb_p = (NP * 64 + 255) / 256;
  k_gather<DPK, true><<<gb_p, 256, 0, stream>>>(pro_x, pstart, pdeg, pcsr, agg, NP);
  k_sage_node<DPK, DPK><<<(NP + 255) / 256, 256, 0, stream>>>(pro_x, agg, c1_Wl, c1_bl, c1_Wr,
                                                              xt1, NP);
  k_gather<DPK, true><<<gb_p, 256, 0, stream>>>(xt1, pstart, pdeg, pcsr, agg, NP);
  k_sage2_pool<<<256, 256, 0, stream>>>(xt1, agg, c2_Wl, c2_bl, c2_Wr, p_batch, poolP, cntP, NP);
  k_head<DP2, 144><<<B, 256, 0, stream>>>(poolP, cntP, pro_W1, pro_b1, pro_W2, pro_b2, prov);

  k_final<<<B, 256, 0, stream>>>(molv, prov, fc1_W, fc1_b, fc2_W, fc2_b, out_W, out_b, out);
}

// Round 2
// 2357.639 us; speedup vs baseline: 1.0883x; 1.0883x over previous
//
#include <hip/hip_runtime.h>

#define K256 __launch_bounds__(256)

constexpr int B = 128;
constexpr int NM = 100000, EM = 400000;
constexpr int NP = 200000, EP = 3200000;
constexpr int DM = 78, DPK = 54, DP2 = 108;

// ---------- CSR build ----------
__global__ void K256 k_count(const int* __restrict__ dst, int* __restrict__ deg, int E) {
  int e = blockIdx.x * 256 + threadIdx.x;
  if (e < E) atomicAdd(&deg[dst[e]], 1);
}

__global__ void k_scan1(const int* __restrict__ deg, int* __restrict__ incl,
                        int* __restrict__ bsum, int N) {
  __shared__ int s[1024];
  int i = blockIdx.x * 1024 + threadIdx.x;
  int v = (i < N) ? deg[i] : 0;
  s[threadIdx.x] = v;
  __syncthreads();
  for (int off = 1; off < 1024; off <<= 1) {
    int t = (threadIdx.x >= off) ? s[threadIdx.x - off] : 0;
    __syncthreads();
    s[threadIdx.x] += t;
    __syncthreads();
  }
  if (i < N) incl[i] = s[threadIdx.x];
  if (threadIdx.x == 1023) bsum[blockIdx.x] = s[1023];
}

__global__ void k_scan2(int* __restrict__ bsum, int nb) {
  __shared__ int s[256];
  int v = (threadIdx.x < (unsigned)nb) ? bsum[threadIdx.x] : 0;
  s[threadIdx.x] = v;
  __syncthreads();
  for (int off = 1; off < 256; off <<= 1) {
    int t = (threadIdx.x >= off) ? s[threadIdx.x - off] : 0;
    __syncthreads();
    s[threadIdx.x] += t;
    __syncthreads();
  }
  if (threadIdx.x < (unsigned)nb) bsum[threadIdx.x] = s[threadIdx.x] - v;  // exclusive
}

__global__ void K256 k_scan3(const int* __restrict__ incl, const int* __restrict__ deg,
                             const int* __restrict__ bsum, int* __restrict__ starts,
                             int* __restrict__ cur, int N) {
  int i = blockIdx.x * 256 + threadIdx.x;
  if (i < N) {
    int v = incl[i] - deg[i] + bsum[i >> 10];
    starts[i] = v;
    cur[i] = v;
  }
}

__global__ void K256 k_fill(const int* __restrict__ src, const int* __restrict__ dst,
                            int* __restrict__ cur, int* __restrict__ csr, int E) {
  int e = blockIdx.x * 256 + threadIdx.x;
  if (e < E) {
    int p = atomicAdd(&cur[dst[e]], 1);
    csr[p] = src[e];
  }
}

// ---------- batch segment starts (batch is sorted) ----------
__global__ void K256 k_bstart(const int* __restrict__ batch, int* __restrict__ bstart, int N) {
  int i = blockIdx.x * 256 + threadIdx.x;
  if (i < N) {
    int b = batch[i];
    int pb = (i == 0) ? -1 : batch[i - 1];
    for (int bb = pb + 1; bb <= b; bb++) bstart[bb] = i;
    if (i == N - 1)
      for (int bb = b + 1; bb <= B; bb++) bstart[bb] = N;
  }
}

// ---------- gather aggregation: wave per node, float2 lanes; 2 edges/iter if D/2<=32 ----------
template <int D, bool MEAN>
__global__ void K256 k_gatherv(const float* __restrict__ x, const int* __restrict__ starts,
                               const int* __restrict__ deg, const int* __restrict__ csr,
                               float* __restrict__ out, int N, int ostride) {
  constexpr int NF2 = D / 2;
  int wid = (blockIdx.x * 256 + threadIdx.x) >> 6;
  int lane = threadIdx.x & 63;
  if (wid >= N) return;
  int s = starts[wid], d = deg[wid];
  const int* cp = csr + s;
  float ax = 0.f, ay = 0.f;
  if constexpr (NF2 <= 32) {
    int half = lane >> 5, sl = lane & 31;
    bool act = sl < NF2;
    for (int j = 0; j < d; j += 2) {
      int e = j + half;
      if (e < d && act) {
        const float2* row = (const float2*)(x + (size_t)cp[e] * D);
        float2 v = row[sl];
        ax += v.x;
        ay += v.y;
      }
    }
    ax += __shfl_xor(ax, 32, 64);
    ay += __shfl_xor(ay, 32, 64);
    if (half == 0 && act) {
      float inv = MEAN ? 1.f / fmaxf((float)d, 1.f) : 1.f;
      float2* op = (float2*)(out + (size_t)wid * ostride);
      float2 w;
      w.x = ax * inv;
      w.y = ay * inv;
      op[sl] = w;
    }
  } else {
    bool act = lane < NF2;
    for (int j = 0; j < d; j++) {
      if (act) {
        const float2* row = (const float2*)(x + (size_t)cp[j] * D);
        float2 v = row[lane];
        ax += v.x;
        ay += v.y;
      }
    }
    if (act) {
      float inv = MEAN ? 1.f / fmaxf((float)d, 1.f) : 1.f;
      float2* op = (float2*)(out + (size_t)wid * ostride);
      float2 w;
      w.x = ax * inv;
      w.y = ay * inv;
      op[lane] = w;
    }
  }
}

// ---------- segmented pooling (no atomics): pooled[b] (+)= coef * sum_{i in seg b} x[i] ----------
template <int D, int NPB, bool ACCUM>
__global__ void K256 k_pool_seg(const float* __restrict__ x, const int* __restrict__ bstart,
                                float* __restrict__ pooled, float coef) {
  __shared__ float sp[D * NPB];
  int b = blockIdx.x, tid = threadIdx.x;
  int r0 = bstart[b], r1 = bstart[b + 1];
  if (tid < D * NPB) {
    int ioff = tid / D, f = tid - ioff * D;
    float acc = 0.f;
    for (int i = r0 + ioff; i < r1; i += NPB) acc += x[(size_t)i * D + f];
    sp[tid] = acc;
  }
  __syncthreads();
  if (tid < D) {
    float s = 0.f;
#pragma unroll
    for (int g = 0; g < NPB; g++) s += sp[g * D + tid];
    s *= coef;
    if (ACCUM)
      pooled[b * D + tid] += s;
    else
      pooled[b * D + tid] = s;
  }
}

// ---------- SAGE node update: out = relu(agg @ Wl^T + bl + x @ Wr^T) ----------
template <int K, int O>
__global__ void K256 k_sage_node(const float* __restrict__ x, const float* __restrict__ agg,
                                 const float* __restrict__ Wl, const float* __restrict__ bl,
                                 const float* __restrict__ Wr, float* __restrict__ out, int N) {
  int i = blockIdx.x * 256 + threadIdx.x;
  if (i >= N) return;
  float xr[K], am[K];
  const float* xp = x + (size_t)i * K;
  const float* ap = agg + (size_t)i * K;
#pragma unroll
  for (int k = 0; k < K; k++) {
    xr[k] = xp[k];
    am[k] = ap[k];
  }
  float* op = out + (size_t)i * O;
#pragma unroll 1
  for (int o = 0; o < O; o += 6) {
    float a0 = bl[o + 0], a1 = bl[o + 1], a2 = bl[o + 2];
    float a3 = bl[o + 3], a4 = bl[o + 4], a5 = bl[o + 5];
#pragma unroll
    for (int k = 0; k < K; k++) {
      float xv = xr[k], av = am[k];
      a0 += av * Wl[(o + 0) * K + k] + xv * Wr[(o + 0) * K + k];
      a1 += av * Wl[(o + 1) * K + k] + xv * Wr[(o + 1) * K + k];
      a2 += av * Wl[(o + 2) * K + k] + xv * Wr[(o + 2) * K + k];
      a3 += av * Wl[(o + 3) * K + k] + xv * Wr[(o + 3) * K + k];
      a4 += av * Wl[(o + 4) * K + k] + xv * Wr[(o + 4) * K + k];
      a5 += av * Wl[(o + 5) * K + k] + xv * Wr[(o + 5) * K + k];
    }
    op[o + 0] = fmaxf(a0, 0.f);
    op[o + 1] = fmaxf(a1, 0.f);
    op[o + 2] = fmaxf(a2, 0.f);
    op[o + 3] = fmaxf(a3, 0.f);
    op[o + 4] = fmaxf(a4, 0.f);
    op[o + 5] = fmaxf(a5, 0.f);
  }
}

// ---------- conv2 node update fused with segment pooling (wave-reduced, no hot atomics) ----------
template <int SPLIT>
__global__ void K256 k_sage2_pool2(const float* __restrict__ xt1, const float* __restrict__ agg,
                                   const float* __restrict__ Wl, const float* __restrict__ bl,
                                   const float* __restrict__ Wr, const int* __restrict__ bstart,
                                   float* __restrict__ pooled) {
  __shared__ float sp[4][DP2];
  int b = blockIdx.x / SPLIT;
  int sidx = blockIdx.x - b * SPLIT;
  int tid = threadIdx.x, w = tid >> 6;
  for (int t = tid; t < 4 * DP2; t += 256) ((float*)sp)[t] = 0.f;
  __syncthreads();
  int r0 = bstart[b], r1 = bstart[b + 1];
  int len = r1 - r0;
  int per = (len + SPLIT - 1) / SPLIT;
  int s0 = r0 + sidx * per;
  int s1 = min(r1, s0 + per);
  for (int i0 = s0; i0 < s1; i0 += 256) {
    int i = i0 + tid;
    bool have = i < s1;
    float xr[DPK], am[DPK];
    if (have) {
      const float* xp = xt1 + (size_t)i * DPK;
      const float* ap = agg + (size_t)i * DPK;
#pragma unroll
      for (int k = 0; k < DPK; k++) {
        xr[k] = xp[k];
        am[k] = ap[k];
      }
    } else {
#pragma unroll
      for (int k = 0; k < DPK; k++) {
        xr[k] = 0.f;
        am[k] = 0.f;
      }
    }
#pragma unroll 1
    for (int o = 0; o < DP2; o += 6) {
      float a0 = 0.f, a1 = 0.f, a2 = 0.f, a3 = 0.f, a4 = 0.f, a5 = 0.f;
#pragma unroll
      for (int k = 0; k < DPK; k++) {
        float xv = xr[k], av = am[k];
        a0 += av * Wl[(o + 0) * DPK + k] + xv * Wr[(o + 0) * DPK + k];
        a1 += av * Wl[(o + 1) * DPK + k] + xv * Wr[(o + 1) * DPK + k];
        a2 += av * Wl[(o + 2) * DPK + k] + xv * Wr[(o + 2) * DPK + k];
        a3 += av * Wl[(o + 3) * DPK + k] + xv * Wr[(o + 3) * DPK + k];
        a4 += av * Wl[(o + 4) * DPK + k] + xv * Wr[(o + 4) * DPK + k];
        a5 += av * Wl[(o + 5) * DPK + k] + xv * Wr[(o + 5) * DPK + k];
      }
      float v0 = have ? fmaxf(a0 + bl[o + 0], 0.f) : 0.f;
      float v1 = have ? fmaxf(a1 + bl[o + 1], 0.f) : 0.f;
      float v2 = have ? fmaxf(a2 + bl[o + 2], 0.f) : 0.f;
      float v3 = have ? fmaxf(a3 + bl[o + 3], 0.f) : 0.f;
      float v4 = have ? fmaxf(a4 + bl[o + 4], 0.f) : 0.f;
      float v5 = have ? fmaxf(a5 + bl[o + 5], 0.f) : 0.f;
#pragma unroll
      for (int off = 1; off < 64; off <<= 1) {
        v0 += __shfl_xor(v0, off, 64);
        v1 += __shfl_xor(v1, off, 64);
        v2 += __shfl_xor(v2, off, 64);
        v3 += __shfl_xor(v3, off, 64);
        v4 += __shfl_xor(v4, off, 64);
        v5 += __shfl_xor(v5, off, 64);
      }
      if ((tid & 63) == 0) {
        sp[w][o + 0] += v0;
        sp[w][o + 1] += v1;
        sp[w][o + 2] += v2;
        sp[w][o + 3] += v3;
        sp[w][o + 4] += v4;
        sp[w][o + 5] += v5;
      }
    }
  }
  __syncthreads();
  for (int f = tid; f < DP2; f += 256) {
    float s = sp[0][f] + sp[1][f] + sp[2][f] + sp[3][f];
    if (s != 0.f) atomicAdd(&pooled[b * DP2 + f], s);
  }
}

// ---------- branch head MLP: mean -> 256 relu -> DOUT (linear) ----------
template <int DIN, int DOUT>
__global__ void K256 k_head(const float* __restrict__ pooled, const int* __restrict__ bstart,
                            const float* __restrict__ W1, const float* __restrict__ b1,
                            const float* __restrict__ W2, const float* __restrict__ b2,
                            float* __restrict__ outv) {
  __shared__ float sx[DIN];
  __shared__ float sh[256];
  int b = blockIdx.x, tid = threadIdx.x;
  float inv = 1.f / fmaxf((float)(bstart[b + 1] - bstart[b]), 1.f);
  for (int f = tid; f < DIN; f += 256) sx[f] = pooled[b * DIN + f] * inv;
  __syncthreads();
  float acc = b1[tid];
#pragma unroll 2
  for (int k = 0; k < DIN; k++) acc += sx[k] * W1[tid * DIN + k];
  sh[tid] = fmaxf(acc, 0.f);
  __syncthreads();
  if (tid < DOUT) {
    float a = b2[tid];
#pragma unroll 4
    for (int k = 0; k < 256; k++) a += sh[k] * W2[tid * 256 + k];
    outv[b * DOUT + tid] = a;
  }
}

// ---------- final: concat -> 1024 relu -> 512 relu -> 1 ----------
__global__ void K256 k_final(const float* __restrict__ molv, const float* __restrict__ prov,
                             const float* __restrict__ W1, const float* __restrict__ b1,
                             const float* __restrict__ W2, const float* __restrict__ b2,
                             const float* __restrict__ W3, const float* __restrict__ b3,
                             float* __restrict__ out) {
  __shared__ float sx[256];
  __shared__ float sh1[1024];
  __shared__ float sh2[512];
  __shared__ float red[4];
  int b = blockIdx.x, tid = threadIdx.x;
  sx[tid] = (tid < 112) ? molv[b * 112 + tid] : prov[b * 144 + (tid - 112)];
  __syncthreads();
  for (int o = tid; o < 1024; o += 256) {
    float a = b1[o];
#pragma unroll 4
    for (int k = 0; k < 256; k++) a += sx[k] * W1[o * 256 + k];
    sh1[o] = fmaxf(a, 0.f);
  }
  __syncthreads();
  for (int o = tid; o < 512; o += 256) {
    float a = b2[o];
#pragma unroll 4
    for (int k = 0; k < 1024; k++) a += sh1[k] * W2[o * 1024 + k];
    sh2[o] = fmaxf(a, 0.f);
  }
  __syncthreads();
  float a = 0.f;
  for (int k = tid; k < 512; k += 256) a += sh2[k] * W3[k];
  for (int off = 32; off > 0; off >>= 1) a += __shfl_down(a, off, 64);
  if ((tid & 63) == 0) red[tid >> 6] = a;
  __syncthreads();
  if (tid == 0) out[b] = red[0] + red[1] + red[2] + red[3] + b3[0];
}

__global__ void k_report(float* out, float v, int n) {
  int i = blockIdx.x * 256 + threadIdx.x;
  if (i < n) out[i] = v;
}

extern "C" void kernel_launch(void* const* d_in, const int* in_sizes, int n_in,
                              void* d_out, int out_size, void* d_ws, size_t ws_size,
                              hipStream_t stream) {
  (void)in_sizes; (void)n_in;
  const float* mol_x = (const float*)d_in[0];
  const int* m_ei = (const int*)d_in[1];
  const int* m_batch = (const int*)d_in[2];
  const float* pro_x = (const float*)d_in[3];
  const int* p_ei = (const int*)d_in[4];
  const int* p_batch = (const int*)d_in[5];
  const float* mol_W1 = (const float*)d_in[6];
  const float* mol_b1 = (const float*)d_in[7];
  const float* mol_W2 = (const float*)d_in[8];
  const float* mol_b2 = (const float*)d_in[9];
  const float* c1_Wl = (const float*)d_in[10];
  const float* c1_bl = (const float*)d_in[11];
  const float* c1_Wr = (const float*)d_in[12];
  const float* c2_Wl = (const float*)d_in[13];
  const float* c2_bl = (const float*)d_in[14];
  const float* c2_Wr = (const float*)d_in[15];
  const float* pro_W1 = (const float*)d_in[16];
  const float* pro_b1 = (const float*)d_in[17];
  const float* pro_W2 = (const float*)d_in[18];
  const float* pro_b2 = (const float*)d_in[19];
  const float* fc1_W = (const float*)d_in[20];
  const float* fc1_b = (const float*)d_in[21];
  const float* fc2_W = (const float*)d_in[22];
  const float* fc2_b = (const float*)d_in[23];
  const float* out_W = (const float*)d_in[24];
  const float* out_b = (const float*)d_in[25];
  float* out = (float*)d_out;
  char* ws = (char*)d_ws;

  const int* m_row = m_ei;       // dst (scatter target of APPNP)
  const int* m_col = m_ei + EM;  // src (gathered)
  const int* p_e0 = p_ei;        // src
  const int* p_e1 = p_ei + EP;   // dst

  auto al = [](size_t x) { return (x + 255) & ~(size_t)255; };

  // pro region (defines union size); mol region overlaps it (phases are sequential)
  size_t o = 0;
  size_t o_pdeg = o;   o += al((size_t)NP * 4);
  size_t o_pincl = o;  o += al((size_t)NP * 4);
  size_t o_pstart = o; o += al((size_t)NP * 4);
  size_t o_pcur = o;   o += al((size_t)NP * 4);
  size_t o_pbsum = o;  o += al(1024);
  size_t o_pcsr = o;   o += al((size_t)EP * 4);
  size_t o_agg = o;    o += al((size_t)NP * DPK * 4);
  size_t o_xt1 = o;    o += al((size_t)NP * DPK * 4);
  size_t pro_end = o;

  o = 0;
  size_t o_mdeg = o;   o += al((size_t)NM * 4);
  size_t o_mincl = o;  o += al((size_t)NM * 4);
  size_t o_mstart = o; o += al((size_t)NM * 4);
  size_t o_mcur = o;   o += al((size_t)NM * 4);
  size_t o_mbsum = o;  o += al(1024);
  size_t o_mcsr = o;   o += al((size_t)EM * 4);
  size_t o_hA = o;     o += al((size_t)NM * DM * 4);
  size_t o_hB = o;     o += al((size_t)NM * DM * 4);
  size_t mol_end = o;

  size_t tail = al(pro_end > mol_end ? pro_end : mol_end);
  size_t o_poolM = tail; tail += al((size_t)B * DM * 4);
  size_t o_poolP = tail; tail += al((size_t)B * DP2 * 4);
  size_t o_molv = tail;  tail += al((size_t)B * 112 * 4);
  size_t o_prov = tail;  tail += al((size_t)B * 144 * 4);
  size_t o_mbs = tail;   tail += al((size_t)(B + 1) * 4);
  size_t o_pbs = tail;   tail += al((size_t)(B + 1) * 4);

  if (ws_size < tail) {
    k_report<<<1, 256, 0, stream>>>(out, (float)(ws_size >> 20), out_size);
    return;
  }

  int* mdeg = (int*)(ws + o_mdeg);
  int* mincl = (int*)(ws + o_mincl);
  int* mstart = (int*)(ws + o_mstart);
  int* mcur = (int*)(ws + o_mcur);
  int* mbsum = (int*)(ws + o_mbsum);
  int* mcsr = (int*)(ws + o_mcsr);
  float* hA = (float*)(ws + o_hA);
  float* hB = (float*)(ws + o_hB);
  int* pdeg = (int*)(ws + o_pdeg);
  int* pincl = (int*)(ws + o_pincl);
  int* pstart = (int*)(ws + o_pstart);
  int* pcur = (int*)(ws + o_pcur);
  int* pbsum = (int*)(ws + o_pbsum);
  int* pcsr = (int*)(ws + o_pcsr);
  float* agg = (float*)(ws + o_agg);
  float* xt1 = (float*)(ws + o_xt1);
  float* poolM = (float*)(ws + o_poolM);
  float* poolP = (float*)(ws + o_poolP);
  float* molv = (float*)(ws + o_molv);
  float* prov = (float*)(ws + o_prov);
  int* mbs = (int*)(ws + o_mbs);
  int* pbs = (int*)(ws + o_pbs);

  // ===== MOL branch =====
  hipMemsetAsync(mdeg, 0, (size_t)NM * 4, stream);
  int eb_m = (EM + 255) / 256;
  k_count<<<eb_m, 256, 0, stream>>>(m_row, mdeg, EM);
  int nb_m = (NM + 1023) / 1024;
  k_scan1<<<nb_m, 1024, 0, stream>>>(mdeg, mincl, mbsum, NM);
  k_scan2<<<1, 256, 0, stream>>>(mbsum, nb_m);
  k_scan3<<<(NM + 255) / 256, 256, 0, stream>>>(mincl, mdeg, mbsum, mstart, mcur, NM);
  k_fill<<<eb_m, 256, 0, stream>>>(m_col, m_row, mcur, mcsr, EM);
  k_bstart<<<(NM + 255) / 256, 256, 0, stream>>>(m_batch, mbs, NM);

  int gb_m = (NM * 64 + 255) / 256;
  k_pool_seg<DM, 3, false><<<B, 256, 0, stream>>>(mol_x, mbs, poolM, 0.05f);
  k_gatherv<DM, false><<<gb_m, 256, 0, stream>>>(mol_x, mstart, mdeg, mcsr, hA, NM, DM);
  k_pool_seg<DM, 3, true><<<B, 256, 0, stream>>>(hA, mbs, poolM, 0.2375f);
  k_gatherv<DM, false><<<gb_m, 256, 0, stream>>>(hA, mstart, mdeg, mcsr, hB, NM, DM);
  k_pool_seg<DM, 3, true><<<B, 256, 0, stream>>>(hB, mbs, poolM, 0.2375f);
  k_gatherv<DM, false><<<gb_m, 256, 0, stream>>>(hB, mstart, mdeg, mcsr, hA, NM, DM);
  k_pool_seg<DM, 3, true><<<B, 256, 0, stream>>>(hA, mbs, poolM, 0.2375f);
  k_gatherv<DM, false><<<gb_m, 256, 0, stream>>>(hA, mstart, mdeg, mcsr, hB, NM, DM);
  k_pool_seg<DM, 3, true><<<B, 256, 0, stream>>>(hB, mbs, poolM, 0.2375f);
  k_head<DM, 112><<<B, 256, 0, stream>>>(poolM, mbs, mol_W1, mol_b1, mol_W2, mol_b2, molv);

  // ===== PRO branch (reuses the mol region) =====
  hipMemsetAsync(pdeg, 0, (size_t)NP * 4, stream);
  hipMemsetAsync(poolP, 0, (size_t)B * DP2 * 4, stream);
  int eb_p = (EP + 255) / 256;
  k_count<<<eb_p, 256, 0, stream>>>(p_e1, pdeg, EP);
  int nb_p = (NP + 1023) / 1024;
  k_scan1<<<nb_p, 1024, 0, stream>>>(pdeg, pincl, pbsum, NP);
  k_scan2<<<1, 256, 0, stream>>>(pbsum, nb_p);
  k_scan3<<<(NP + 255) / 256, 256, 0, stream>>>(pincl, pdeg, pbsum, pstart, pcur, NP);
  k_fill<<<eb_p, 256, 0, stream>>>(p_e0, p_e1, pcur, pcsr, EP);
  k_bstart<<<(NP + 255) / 256, 256, 0, stream>>>(p_batch, pbs, NP);

  int gb_p = (NP * 64 + 255) / 256;
  k_gatherv<DPK, true><<<gb_p, 256, 0, stream>>>(pro_x, pstart, pdeg, pcsr, agg, NP, DPK);
  k_sage_node<DPK, DPK><<<(NP + 255) / 256, 256, 0, stream>>>(pro_x, agg, c1_Wl, c1_bl, c1_Wr,
                                                              xt1, NP);
  k_gatherv<DPK, true><<<gb_p, 256, 0, stream>>>(xt1, pstart, pdeg, pcsr, agg, NP, DPK);
  k_sage2_pool2<8><<<B * 8, 256, 0, stream>>>(xt1, agg, c2_Wl, c2_bl, c2_Wr, pbs, poolP);
  k_head<DP2, 144><<<B, 256, 0, stream>>>(poolP, pbs, pro_W1, pro_b1, pro_W2, pro_b2, prov);

  k_final<<<B, 256, 0, stream>>>(molv, prov, fc1_W, fc1_b, fc2_W, fc2_b, out_W, out_b, out);
}

// Round 3
// 2033.124 us; speedup vs baseline: 1.2620x; 1.1596x over previous
//
#include <hip/hip_runtime.h>

#define K256 __launch_bounds__(256)

constexpr int B = 128;
constexpr int NM = 100000, EM = 400000;
constexpr int NP = 200000, EP = 3200000;
constexpr int DM = 78, DPK = 54, DP2 = 108;

// ---------- CSR build ----------
__global__ void K256 k_count(const int* __restrict__ dst, int* __restrict__ deg, int E) {
  int e = blockIdx.x * 256 + threadIdx.x;
  if (e < E) atomicAdd(&deg[dst[e]], 1);
}

__global__ void k_scan1(const int* __restrict__ deg, int* __restrict__ incl,
                        int* __restrict__ bsum, int N) {
  __shared__ int s[1024];
  int i = blockIdx.x * 1024 + threadIdx.x;
  int v = (i < N) ? deg[i] : 0;
  s[threadIdx.x] = v;
  __syncthreads();
  for (int off = 1; off < 1024; off <<= 1) {
    int t = (threadIdx.x >= off) ? s[threadIdx.x - off] : 0;
    __syncthreads();
    s[threadIdx.x] += t;
    __syncthreads();
  }
  if (i < N) incl[i] = s[threadIdx.x];
  if (threadIdx.x == 1023) bsum[blockIdx.x] = s[1023];
}

__global__ void k_scan2(int* __restrict__ bsum, int nb) {
  __shared__ int s[256];
  int v = (threadIdx.x < (unsigned)nb) ? bsum[threadIdx.x] : 0;
  s[threadIdx.x] = v;
  __syncthreads();
  for (int off = 1; off < 256; off <<= 1) {
    int t = (threadIdx.x >= off) ? s[threadIdx.x - off] : 0;
    __syncthreads();
    s[threadIdx.x] += t;
    __syncthreads();
  }
  if (threadIdx.x < (unsigned)nb) bsum[threadIdx.x] = s[threadIdx.x] - v;  // exclusive
}

__global__ void K256 k_scan3(const int* __restrict__ incl, const int* __restrict__ deg,
                             const int* __restrict__ bsum, int* __restrict__ starts,
                             int* __restrict__ cur, int N) {
  int i = blockIdx.x * 256 + threadIdx.x;
  if (i < N) {
    int v = incl[i] - deg[i] + bsum[i >> 10];
    starts[i] = v;
    cur[i] = v;
  }
}

__global__ void K256 k_fill(const int* __restrict__ src, const int* __restrict__ dst,
                            int* __restrict__ cur, int* __restrict__ csr, int E) {
  int e = blockIdx.x * 256 + threadIdx.x;
  if (e < E) {
    int p = atomicAdd(&cur[dst[e]], 1);
    csr[p] = src[e];
  }
}

// ---------- batch segment starts (batch is sorted) ----------
__global__ void K256 k_bstart(const int* __restrict__ batch, int* __restrict__ bstart, int N) {
  int i = blockIdx.x * 256 + threadIdx.x;
  if (i < N) {
    int b = batch[i];
    int pb = (i == 0) ? -1 : batch[i - 1];
    for (int bb = pb + 1; bb <= b; bb++) bstart[bb] = i;
    if (i == N - 1)
      for (int bb = b + 1; bb <= B; bb++) bstart[bb] = N;
  }
}

// ---------- small transpose: out[c*R + r] = in[r*C + c] ----------
__global__ void K256 k_trans(const float* __restrict__ in, float* __restrict__ out, int R, int C) {
  int i = blockIdx.x * 256 + threadIdx.x;
  if (i < R * C) {
    int r = i / C, c = i - r * C;
    out[c * R + r] = in[i];
  }
}

// ---------- gather aggregation: wave per node, float2 lanes; 2 edges/iter if D/2<=32 ----------
template <int D, bool MEAN>
__global__ void K256 k_gatherv(const float* __restrict__ x, const int* __restrict__ starts,
                               const int* __restrict__ deg, const int* __restrict__ csr,
                               float* __restrict__ out, int N, int ostride) {
  constexpr int NF2 = D / 2;
  int wid = (blockIdx.x * 256 + threadIdx.x) >> 6;
  int lane = threadIdx.x & 63;
  if (wid >= N) return;
  int s = starts[wid], d = deg[wid];
  const int* cp = csr + s;
  float ax = 0.f, ay = 0.f;
  if constexpr (NF2 <= 32) {
    int half = lane >> 5, sl = lane & 31;
    bool act = sl < NF2;
    for (int j = 0; j < d; j += 2) {
      int e = j + half;
      if (e < d && act) {
        const float2* row = (const float2*)(x + (size_t)cp[e] * D);
        float2 v = row[sl];
        ax += v.x;
        ay += v.y;
      }
    }
    ax += __shfl_xor(ax, 32, 64);
    ay += __shfl_xor(ay, 32, 64);
    if (half == 0 && act) {
      float inv = MEAN ? 1.f / fmaxf((float)d, 1.f) : 1.f;
      float2* op = (float2*)(out + (size_t)wid * ostride);
      float2 w;
      w.x = ax * inv;
      w.y = ay * inv;
      op[sl] = w;
    }
  } else {
    bool act = lane < NF2;
    for (int j = 0; j < d; j++) {
      if (act) {
        const float2* row = (const float2*)(x + (size_t)cp[j] * D);
        float2 v = row[lane];
        ax += v.x;
        ay += v.y;
      }
    }
    if (act) {
      float inv = MEAN ? 1.f / fmaxf((float)d, 1.f) : 1.f;
      float2* op = (float2*)(out + (size_t)wid * ostride);
      float2 w;
      w.x = ax * inv;
      w.y = ay * inv;
      op[lane] = w;
    }
  }
}

// ---------- segmented pooling (no atomics): pooled[b] (+)= coef * sum_{i in seg b} x[i] ----------
template <int D, int NPB, bool ACCUM>
__global__ void K256 k_pool_seg(const float* __restrict__ x, const int* __restrict__ bstart,
                                float* __restrict__ pooled, float coef) {
  __shared__ float sp[D * NPB];
  int b = blockIdx.x, tid = threadIdx.x;
  int r0 = bstart[b], r1 = bstart[b + 1];
  if (tid < D * NPB) {
    int ioff = tid / D, f = tid - ioff * D;
    float acc = 0.f;
    for (int i = r0 + ioff; i < r1; i += NPB) acc += x[(size_t)i * D + f];
    sp[tid] = acc;
  }
  __syncthreads();
  if (tid < D) {
    float s = 0.f;
#pragma unroll
    for (int g = 0; g < NPB; g++) s += sp[g * D + tid];
    s *= coef;
    if (ACCUM)
      pooled[b * D + tid] += s;
    else
      pooled[b * D + tid] = s;
  }
}

// ---------- SAGE conv1 node update, K-streaming, transposed scalar weights ----------
// out[i][o] = relu( sum_k agg[i][k]*WlT[k][o] + x[i][k]*WrT[k][o] + bl[o] )
__global__ void __launch_bounds__(256, 4) k_sage_nodeT(
    const float* __restrict__ x, const float* __restrict__ agg,
    const float* __restrict__ WlT, const float* __restrict__ bl,
    const float* __restrict__ WrT, float* __restrict__ out, int N) {
  int i = blockIdx.x * 256 + threadIdx.x;
  if (i >= N) return;
  float acc[DPK];
#pragma unroll
  for (int o = 0; o < DPK; o++) acc[o] = bl[o];
  const float2* xp = (const float2*)(x + (size_t)i * DPK);
  const float2* ap = (const float2*)(agg + (size_t)i * DPK);
#pragma unroll 2
  for (int k2 = 0; k2 < DPK / 2; k2++) {
    float2 xv = xp[k2];
    float2 av = ap[k2];
    const float* wl = WlT + (2 * k2) * DPK;
    const float* wr = WrT + (2 * k2) * DPK;
#pragma unroll
    for (int o = 0; o < DPK; o++) acc[o] += av.x * wl[o] + xv.x * wr[o];
#pragma unroll
    for (int o = 0; o < DPK; o++) acc[o] += av.y * wl[DPK + o] + xv.y * wr[DPK + o];
  }
  float2* op = (float2*)(out + (size_t)i * DPK);
#pragma unroll
  for (int o2 = 0; o2 < DPK / 2; o2++) {
    float2 w;
    w.x = fmaxf(acc[2 * o2 + 0], 0.f);
    w.y = fmaxf(acc[2 * o2 + 1], 0.f);
    op[o2] = w;
  }
}

// ---------- conv2 + segment-mean pool, K-streaming, output halves, per-thread pool ----------
template <int SPLIT>
__global__ void __launch_bounds__(256, 2) k_sage2_poolT(
    const float* __restrict__ xt1, const float* __restrict__ agg,
    const float* __restrict__ WlT, const float* __restrict__ bl,
    const float* __restrict__ WrT, const int* __restrict__ bstart,
    float* __restrict__ pooled) {
  constexpr int OH = DP2 / 2;  // 54 outputs per half
  int b = blockIdx.x / SPLIT;
  int sidx = blockIdx.x - b * SPLIT;
  int obase = blockIdx.y * OH;
  int tid = threadIdx.x;
  int r0 = bstart[b], r1 = bstart[b + 1];
  int len = r1 - r0;
  int per = (len + SPLIT - 1) / SPLIT;
  int s0 = r0 + sidx * per;
  int s1 = min(r1, s0 + per);
  float pool[OH];
#pragma unroll
  for (int o = 0; o < OH; o++) pool[o] = 0.f;
  for (int i = s0 + tid; i < s1; i += 256) {
    float acc[OH];
#pragma unroll
    for (int o = 0; o < OH; o++) acc[o] = bl[obase + o];
    const float2* xp = (const float2*)(xt1 + (size_t)i * DPK);
    const float2* ap = (const float2*)(agg + (size_t)i * DPK);
#pragma unroll 2
    for (int k2 = 0; k2 < DPK / 2; k2++) {
      float2 xv = xp[k2];
      float2 av = ap[k2];
      const float* wl = WlT + (2 * k2) * DP2 + obase;
      const float* wr = WrT + (2 * k2) * DP2 + obase;
#pragma unroll
      for (int o = 0; o < OH; o++) acc[o] += av.x * wl[o] + xv.x * wr[o];
#pragma unroll
      for (int o = 0; o < OH; o++) acc[o] += av.y * wl[DP2 + o] + xv.y * wr[DP2 + o];
    }
#pragma unroll
    for (int o = 0; o < OH; o++) pool[o] += fmaxf(acc[o], 0.f);
  }
  // once-per-block wave reduction, then 54 atomics from lane 0 of each wave
#pragma unroll
  for (int o = 0; o < OH; o++) {
#pragma unroll
    for (int off = 1; off < 64; off <<= 1) pool[o] += __shfl_xor(pool[o], off, 64);
  }
  if ((tid & 63) == 0) {
    float* pb = pooled + b * DP2 + obase;
#pragma unroll
    for (int o = 0; o < OH; o++)
      if (pool[o] != 0.f) atomicAdd(&pb[o], pool[o]);
  }
}

// ---------- branch head MLP: mean -> 256 relu -> DOUT (linear) ----------
template <int DIN, int DOUT>
__global__ void K256 k_head(const float* __restrict__ pooled, const int* __restrict__ bstart,
                            const float* __restrict__ W1, const float* __restrict__ b1,
                            const float* __restrict__ W2, const float* __restrict__ b2,
                            float* __restrict__ outv) {
  __shared__ float sx[DIN];
  __shared__ float sh[256];
  int b = blockIdx.x, tid = threadIdx.x;
  float inv = 1.f / fmaxf((float)(bstart[b + 1] - bstart[b]), 1.f);
  for (int f = tid; f < DIN; f += 256) sx[f] = pooled[b * DIN + f] * inv;
  __syncthreads();
  float acc = b1[tid];
#pragma unroll 2
  for (int k = 0; k < DIN; k++) acc += sx[k] * W1[tid * DIN + k];
  sh[tid] = fmaxf(acc, 0.f);
  __syncthreads();
  if (tid < DOUT) {
    float a = b2[tid];
#pragma unroll 4
    for (int k = 0; k < 256; k++) a += sh[k] * W2[tid * 256 + k];
    outv[b * DOUT + tid] = a;
  }
}

// ---------- final: concat -> 1024 relu -> 512 relu -> 1 ----------
__global__ void K256 k_final(const float* __restrict__ molv, const float* __restrict__ prov,
                             const float* __restrict__ W1, const float* __restrict__ b1,
                             const float* __restrict__ W2, const float* __restrict__ b2,
                             const float* __restrict__ W3, const float* __restrict__ b3,
                             float* __restrict__ out) {
  __shared__ float sx[256];
  __shared__ float sh1[1024];
  __shared__ float sh2[512];
  __shared__ float red[4];
  int b = blockIdx.x, tid = threadIdx.x;
  sx[tid] = (tid < 112) ? molv[b * 112 + tid] : prov[b * 144 + (tid - 112)];
  __syncthreads();
  for (int o = tid; o < 1024; o += 256) {
    float a = b1[o];
#pragma unroll 4
    for (int k = 0; k < 256; k++) a += sx[k] * W1[o * 256 + k];
    sh1[o] = fmaxf(a, 0.f);
  }
  __syncthreads();
  for (int o = tid; o < 512; o += 256) {
    float a = b2[o];
#pragma unroll 4
    for (int k = 0; k < 1024; k++) a += sh1[k] * W2[o * 1024 + k];
    sh2[o] = fmaxf(a, 0.f);
  }
  __syncthreads();
  float a = 0.f;
  for (int k = tid; k < 512; k += 256) a += sh2[k] * W3[k];
  for (int off = 32; off > 0; off >>= 1) a += __shfl_down(a, off, 64);
  if ((tid & 63) == 0) red[tid >> 6] = a;
  __syncthreads();
  if (tid == 0) out[b] = red[0] + red[1] + red[2] + red[3] + b3[0];
}

__global__ void k_report(float* out, float v, int n) {
  int i = blockIdx.x * 256 + threadIdx.x;
  if (i < n) out[i] = v;
}

extern "C" void kernel_launch(void* const* d_in, const int* in_sizes, int n_in,
                              void* d_out, int out_size, void* d_ws, size_t ws_size,
                              hipStream_t stream) {
  (void)in_sizes; (void)n_in;
  const float* mol_x = (const float*)d_in[0];
  const int* m_ei = (const int*)d_in[1];
  const int* m_batch = (const int*)d_in[2];
  const float* pro_x = (const float*)d_in[3];
  const int* p_ei = (const int*)d_in[4];
  const int* p_batch = (const int*)d_in[5];
  const float* mol_W1 = (const float*)d_in[6];
  const float* mol_b1 = (const float*)d_in[7];
  const float* mol_W2 = (const float*)d_in[8];
  const float* mol_b2 = (const float*)d_in[9];
  const float* c1_Wl = (const float*)d_in[10];
  const float* c1_bl = (const float*)d_in[11];
  const float* c1_Wr = (const float*)d_in[12];
  const float* c2_Wl = (const float*)d_in[13];
  const float* c2_bl = (const float*)d_in[14];
  const float* c2_Wr = (const float*)d_in[15];
  const float* pro_W1 = (const float*)d_in[16];
  const float* pro_b1 = (const float*)d_in[17];
  const float* pro_W2 = (const float*)d_in[18];
  const float* pro_b2 = (const float*)d_in[19];
  const float* fc1_W = (const float*)d_in[20];
  const float* fc1_b = (const float*)d_in[21];
  const float* fc2_W = (const float*)d_in[22];
  const float* fc2_b = (const float*)d_in[23];
  const float* out_W = (const float*)d_in[24];
  const float* out_b = (const float*)d_in[25];
  float* out = (float*)d_out;
  char* ws = (char*)d_ws;

  const int* m_row = m_ei;       // dst (scatter target of APPNP)
  const int* m_col = m_ei + EM;  // src (gathered)
  const int* p_e0 = p_ei;        // src
  const int* p_e1 = p_ei + EP;   // dst

  auto al = [](size_t x) { return (x + 255) & ~(size_t)255; };

  // pro region (defines union size); mol region overlaps it (phases are sequential)
  size_t o = 0;
  size_t o_pdeg = o;   o += al((size_t)NP * 4);
  size_t o_pincl = o;  o += al((size_t)NP * 4);
  size_t o_pstart = o; o += al((size_t)NP * 4);
  size_t o_pcur = o;   o += al((size_t)NP * 4);
  size_t o_pbsum = o;  o += al(1024);
  size_t o_pcsr = o;   o += al((size_t)EP * 4);
  size_t o_agg = o;    o += al((size_t)NP * DPK * 4);
  size_t o_xt1 = o;    o += al((size_t)NP * DPK * 4);
  size_t pro_end = o;

  o = 0;
  size_t o_mdeg = o;   o += al((size_t)NM * 4);
  size_t o_mincl = o;  o += al((size_t)NM * 4);
  size_t o_mstart = o; o += al((size_t)NM * 4);
  size_t o_mcur = o;   o += al((size_t)NM * 4);
  size_t o_mbsum = o;  o += al(1024);
  size_t o_mcsr = o;   o += al((size_t)EM * 4);
  size_t o_hA = o;     o += al((size_t)NM * DM * 4);
  size_t o_hB = o;     o += al((size_t)NM * DM * 4);
  size_t mol_end = o;

  size_t tail = al(pro_end > mol_end ? pro_end : mol_end);
  size_t o_poolM = tail; tail += al((size_t)B * DM * 4);
  size_t o_poolP = tail; tail += al((size_t)B * DP2 * 4);
  size_t o_molv = tail;  tail += al((size_t)B * 112 * 4);
  size_t o_prov = tail;  tail += al((size_t)B * 144 * 4);
  size_t o_mbs = tail;   tail += al((size_t)(B + 1) * 4);
  size_t o_pbs = tail;   tail += al((size_t)(B + 1) * 4);
  size_t o_w1l = tail;   tail += al((size_t)DPK * DPK * 4);
  size_t o_w1r = tail;   tail += al((size_t)DPK * DPK * 4);
  size_t o_w2l = tail;   tail += al((size_t)DPK * DP2 * 4);
  size_t o_w2r = tail;   tail += al((size_t)DPK * DP2 * 4);

  if (ws_size < tail) {
    k_report<<<1, 256, 0, stream>>>(out, (float)(ws_size >> 20), out_size);
    return;
  }

  int* mdeg = (int*)(ws + o_mdeg);
  int* mincl = (int*)(ws + o_mincl);
  int* mstart = (int*)(ws + o_mstart);
  int* mcur = (int*)(ws + o_mcur);
  int* mbsum = (int*)(ws + o_mbsum);
  int* mcsr = (int*)(ws + o_mcsr);
  float* hA = (float*)(ws + o_hA);
  float* hB = (float*)(ws + o_hB);
  int* pdeg = (int*)(ws + o_pdeg);
  int* pincl = (int*)(ws + o_pincl);
  int* pstart = (int*)(ws + o_pstart);
  int* pcur = (int*)(ws + o_pcur);
  int* pbsum = (int*)(ws + o_pbsum);
  int* pcsr = (int*)(ws + o_pcsr);
  float* agg = (float*)(ws + o_agg);
  float* xt1 = (float*)(ws + o_xt1);
  float* poolM = (float*)(ws + o_poolM);
  float* poolP = (float*)(ws + o_poolP);
  float* molv = (float*)(ws + o_molv);
  float* prov = (float*)(ws + o_prov);
  int* mbs = (int*)(ws + o_mbs);
  int* pbs = (int*)(ws + o_pbs);
  float* w1l = (float*)(ws + o_w1l);
  float* w1r = (float*)(ws + o_w1r);
  float* w2l = (float*)(ws + o_w2l);
  float* w2r = (float*)(ws + o_w2r);

  // weight transposes (tiny; only needed before the pro branch)
  k_trans<<<(DPK * DPK + 255) / 256, 256, 0, stream>>>(c1_Wl, w1l, DPK, DPK);
  k_trans<<<(DPK * DPK + 255) / 256, 256, 0, stream>>>(c1_Wr, w1r, DPK, DPK);
  k_trans<<<(DP2 * DPK + 255) / 256, 256, 0, stream>>>(c2_Wl, w2l, DP2, DPK);
  k_trans<<<(DP2 * DPK + 255) / 256, 256, 0, stream>>>(c2_Wr, w2r, DP2, DPK);

  // ===== MOL branch =====
  hipMemsetAsync(mdeg, 0, (size_t)NM * 4, stream);
  int eb_m = (EM + 255) / 256;
  k_count<<<eb_m, 256, 0, stream>>>(m_row, mdeg, EM);
  int nb_m = (NM + 1023) / 1024;
  k_scan1<<<nb_m, 1024, 0, stream>>>(mdeg, mincl, mbsum, NM);
  k_scan2<<<1, 256, 0, stream>>>(mbsum, nb_m);
  k_scan3<<<(NM + 255) / 256, 256, 0, stream>>>(mincl, mdeg, mbsum, mstart, mcur, NM);
  k_fill<<<eb_m, 256, 0, stream>>>(m_col, m_row, mcur, mcsr, EM);
  k_bstart<<<(NM + 255) / 256, 256, 0, stream>>>(m_batch, mbs, NM);

  int gb_m = (NM * 64 + 255) / 256;
  k_pool_seg<DM, 3, false><<<B, 256, 0, stream>>>(mol_x, mbs, poolM, 0.05f);
  k_gatherv<DM, false><<<gb_m, 256, 0, stream>>>(mol_x, mstart, mdeg, mcsr, hA, NM, DM);
  k_pool_seg<DM, 3, true><<<B, 256, 0, stream>>>(hA, mbs, poolM, 0.2375f);
  k_gatherv<DM, false><<<gb_m, 256, 0, stream>>>(hA, mstart, mdeg, mcsr, hB, NM, DM);
  k_pool_seg<DM, 3, true><<<B, 256, 0, stream>>>(hB, mbs, poolM, 0.2375f);
  k_gatherv<DM, false><<<gb_m, 256, 0, stream>>>(hB, mstart, mdeg, mcsr, hA, NM, DM);
  k_pool_seg<DM, 3, true><<<B, 256, 0, stream>>>(hA, mbs, poolM, 0.2375f);
  k_gatherv<DM, false><<<gb_m, 256, 0, stream>>>(hA, mstart, mdeg, mcsr, hB, NM, DM);
  k_pool_seg<DM, 3, true><<<B, 256, 0, stream>>>(hB, mbs, poolM, 0.2375f);
  k_head<DM, 112><<<B, 256, 0, stream>>>(poolM, mbs, mol_W1, mol_b1, mol_W2, mol_b2, molv);

  // ===== PRO branch (reuses the mol region) =====
  hipMemsetAsync(pdeg, 0, (size_t)NP * 4, stream);
  hipMemsetAsync(poolP, 0, (size_t)B * DP2 * 4, stream);
  int eb_p = (EP + 255) / 256;
  k_count<<<eb_p, 256, 0, stream>>>(p_e1, pdeg, EP);
  int nb_p = (NP + 1023) / 1024;
  k_scan1<<<nb_p, 1024, 0, stream>>>(pdeg, pincl, pbsum, NP);
  k_scan2<<<1, 256, 0, stream>>>(pbsum, nb_p);
  k_scan3<<<(NP + 255) / 256, 256, 0, stream>>>(pincl, pdeg, pbsum, pstart, pcur, NP);
  k_fill<<<eb_p, 256, 0, stream>>>(p_e0, p_e1, pcur, pcsr, EP);
  k_bstart<<<(NP + 255) / 256, 256, 0, stream>>>(p_batch, pbs, NP);

  int gb_p = (NP * 64 + 255) / 256;
  k_gatherv<DPK, true><<<gb_p, 256, 0, stream>>>(pro_x, pstart, pdeg, pcsr, agg, NP, DPK);
  k_sage_nodeT<<<(NP + 255) / 256, 256, 0, stream>>>(pro_x, agg, w1l, c1_bl, w1r, xt1, NP);
  k_gatherv<DPK, true><<<gb_p, 256, 0, stream>>>(xt1, pstart, pdeg, pcsr, agg, NP, DPK);
  {
    dim3 g2(B * 4, 2);
    k_sage2_poolT<4><<<g2, 256, 0, stream>>>(xt1, agg, w2l, c2_bl, w2r, pbs, poolP);
  }
  k_head<DP2, 144><<<B, 256, 0, stream>>>(poolP, pbs, pro_W1, pro_b1, pro_W2, pro_b2, prov);

  k_final<<<B, 256, 0, stream>>>(molv, prov, fc1_W, fc1_b, fc2_W, fc2_b, out_W, out_b, out);
}

// Round 4
// 1839.117 us; speedup vs baseline: 1.3951x; 1.1055x over previous
//
#include <hip/hip_runtime.h>

#define K256 __launch_bounds__(256)

constexpr int B = 128;
constexpr int NM = 100000, EM = 400000;
constexpr int NP = 200000, EP = 3200000;
constexpr int DM = 78, DPK = 54, DP2 = 108;

// ---------- CSR build ----------
__global__ void K256 k_count4(const int4* __restrict__ dst, int* __restrict__ deg, int E4) {
  int e = blockIdx.x * 256 + threadIdx.x;
  if (e < E4) {
    int4 v = dst[e];
    atomicAdd(&deg[v.x], 1);
    atomicAdd(&deg[v.y], 1);
    atomicAdd(&deg[v.z], 1);
    atomicAdd(&deg[v.w], 1);
  }
}

__global__ void k_scan1(const int* __restrict__ deg, int* __restrict__ incl,
                        int* __restrict__ bsum, int N) {
  __shared__ int s[1024];
  int i = blockIdx.x * 1024 + threadIdx.x;
  int v = (i < N) ? deg[i] : 0;
  s[threadIdx.x] = v;
  __syncthreads();
  for (int off = 1; off < 1024; off <<= 1) {
    int t = (threadIdx.x >= off) ? s[threadIdx.x - off] : 0;
    __syncthreads();
    s[threadIdx.x] += t;
    __syncthreads();
  }
  if (i < N) incl[i] = s[threadIdx.x];
  if (threadIdx.x == 1023) bsum[blockIdx.x] = s[1023];
}

__global__ void k_scan2(int* __restrict__ bsum, int nb) {
  __shared__ int s[256];
  int v = (threadIdx.x < (unsigned)nb) ? bsum[threadIdx.x] : 0;
  s[threadIdx.x] = v;
  __syncthreads();
  for (int off = 1; off < 256; off <<= 1) {
    int t = (threadIdx.x >= off) ? s[threadIdx.x - off] : 0;
    __syncthreads();
    s[threadIdx.x] += t;
    __syncthreads();
  }
  if (threadIdx.x < (unsigned)nb) bsum[threadIdx.x] = s[threadIdx.x] - v;  // exclusive
}

__global__ void K256 k_scan3(const int* __restrict__ incl, const int* __restrict__ deg,
                             const int* __restrict__ bsum, int* __restrict__ starts, int N) {
  int i = blockIdx.x * 256 + threadIdx.x;
  if (i < N) starts[i] = incl[i] - deg[i] + bsum[i >> 10];
}

// bucket cursor init: bcur[b] = starts[b << SH]
template <int SH>
__global__ void K256 k_bcur(const int* __restrict__ starts, int* __restrict__ bcur, int N) {
  int b = blockIdx.x * 256 + threadIdx.x;
  int NB = (N + (1 << SH) - 1) >> SH;
  if (b < NB) bcur[b] = starts[b << SH];
}

// Pass A: bucket-grouped edge binning (counting-sort per 4096-edge chunk).
// Writes (src,dst) pairs grouped by bucket so the CSR fill has L2-resident targets.
template <int SH>
__global__ void K256 k_bin(const int* __restrict__ src, const int* __restrict__ dst,
                           int* __restrict__ bcur, int2* __restrict__ binned, int E) {
  __shared__ int lh[512];
  __shared__ int gbase[512];
  int c0 = blockIdx.x * 4096;
  int tid = threadIdx.x;
  for (int t = tid; t < 512; t += 256) lh[t] = 0;
  __syncthreads();
  int r[16], dcache[16];
#pragma unroll
  for (int k = 0; k < 16; k++) {
    int e = c0 + k * 256 + tid;
    if (e < E) {
      int d = dst[e];
      dcache[k] = d;
      r[k] = atomicAdd(&lh[d >> SH], 1);
    }
  }
  __syncthreads();
  for (int b = tid; b < 512; b += 256) {
    int c = lh[b];
    gbase[b] = c ? atomicAdd(&bcur[b], c) : 0;
  }
  __syncthreads();
#pragma unroll
  for (int k = 0; k < 16; k++) {
    int e = c0 + k * 256 + tid;
    if (e < E) {
      int d = dcache[k];
      binned[gbase[d >> SH] + r[k]] = make_int2(src[e], d);
    }
  }
}

// Pass B: per-bucket CSR fill; node cursors in LDS, writes confined to one L2-hot region.
template <int SH>
__global__ void K256 k_fill2(const int2* __restrict__ binned, const int* __restrict__ starts,
                             int* __restrict__ csr, int N, int E) {
  __shared__ int lcur[1 << SH];
  int b = blockIdx.x;
  int base = b << SH;
  int nn = min(N - base, 1 << SH);
  int tid = threadIdx.x;
  for (int t = tid; t < nn; t += 256) lcur[t] = starts[base + t];
  __syncthreads();
  int r0 = starts[base];
  int r1 = (base + (1 << SH) >= N) ? E : starts[base + (1 << SH)];
  for (int e = r0 + tid; e < r1; e += 256) {
    int2 sd = binned[e];
    int p = atomicAdd(&lcur[sd.y - base], 1);
    csr[p] = sd.x;
  }
}

// ---------- batch segment starts (batch is sorted) ----------
__global__ void K256 k_bstart(const int* __restrict__ batch, int* __restrict__ bstart, int N) {
  int i = blockIdx.x * 256 + threadIdx.x;
  if (i < N) {
    int b = batch[i];
    int pb = (i == 0) ? -1 : batch[i - 1];
    for (int bb = pb + 1; bb <= b; bb++) bstart[bb] = i;
    if (i == N - 1)
      for (int bb = b + 1; bb <= B; bb++) bstart[bb] = N;
  }
}

// ---------- small transpose: out[c*R + r] = in[r*C + c] ----------
__global__ void K256 k_trans(const float* __restrict__ in, float* __restrict__ out, int R, int C) {
  int i = blockIdx.x * 256 + threadIdx.x;
  if (i < R * C) {
    int r = i / C, c = i - r * C;
    out[c * R + r] = in[i];
  }
}

// ---------- gather aggregation: wave per node, float2 lanes; 2 edges/iter if D/2<=32 ----------
template <int D, bool MEAN>
__global__ void K256 k_gatherv(const float* __restrict__ x, const int* __restrict__ starts,
                               const int* __restrict__ deg, const int* __restrict__ csr,
                               float* __restrict__ out, int N, int ostride) {
  constexpr int NF2 = D / 2;
  int wid = (blockIdx.x * 256 + threadIdx.x) >> 6;
  int lane = threadIdx.x & 63;
  if (wid >= N) return;
  int s = starts[wid], d = deg[wid];
  const int* cp = csr + s;
  float ax = 0.f, ay = 0.f;
  if constexpr (NF2 <= 32) {
    int half = lane >> 5, sl = lane & 31;
    bool act = sl < NF2;
    for (int j = 0; j < d; j += 2) {
      int e = j + half;
      if (e < d && act) {
        const float2* row = (const float2*)(x + (size_t)cp[e] * D);
        float2 v = row[sl];
        ax += v.x;
        ay += v.y;
      }
    }
    ax += __shfl_xor(ax, 32, 64);
    ay += __shfl_xor(ay, 32, 64);
    if (half == 0 && act) {
      float inv = MEAN ? 1.f / fmaxf((float)d, 1.f) : 1.f;
      float2* op = (float2*)(out + (size_t)wid * ostride);
      float2 w;
      w.x = ax * inv;
      w.y = ay * inv;
      op[sl] = w;
    }
  } else {
    bool act = lane < NF2;
    for (int j = 0; j < d; j++) {
      if (act) {
        const float2* row = (const float2*)(x + (size_t)cp[j] * D);
        float2 v = row[lane];
        ax += v.x;
        ay += v.y;
      }
    }
    if (act) {
      float inv = MEAN ? 1.f / fmaxf((float)d, 1.f) : 1.f;
      float2* op = (float2*)(out + (size_t)wid * ostride);
      float2 w;
      w.x = ax * inv;
      w.y = ay * inv;
      op[lane] = w;
    }
  }
}

// ---------- segmented pooling (no atomics): pooled[b] (+)= coef * sum_{i in seg b} x[i] ----------
template <int D, int NPB, bool ACCUM>
__global__ void K256 k_pool_seg(const float* __restrict__ x, const int* __restrict__ bstart,
                                float* __restrict__ pooled, float coef) {
  __shared__ float sp[D * NPB];
  int b = blockIdx.x, tid = threadIdx.x;
  int r0 = bstart[b], r1 = bstart[b + 1];
  if (tid < D * NPB) {
    int ioff = tid / D, f = tid - ioff * D;
    float acc = 0.f;
    for (int i = r0 + ioff; i < r1; i += NPB) acc += x[(size_t)i * D + f];
    sp[tid] = acc;
  }
  __syncthreads();
  if (tid < D) {
    float s = 0.f;
#pragma unroll
    for (int g = 0; g < NPB; g++) s += sp[g * D + tid];
    s *= coef;
    if (ACCUM)
      pooled[b * D + tid] += s;
    else
      pooled[b * D + tid] = s;
  }
}

// ---------- SAGE conv1 node update, K-streaming, transposed scalar weights ----------
__global__ void __launch_bounds__(256, 4) k_sage_nodeT(
    const float* __restrict__ x, const float* __restrict__ agg,
    const float* __restrict__ WlT, const float* __restrict__ bl,
    const float* __restrict__ WrT, float* __restrict__ out, int N) {
  int i = blockIdx.x * 256 + threadIdx.x;
  if (i >= N) return;
  float acc[DPK];
#pragma unroll
  for (int o = 0; o < DPK; o++) acc[o] = bl[o];
  const float2* xp = (const float2*)(x + (size_t)i * DPK);
  const float2* ap = (const float2*)(agg + (size_t)i * DPK);
#pragma unroll 2
  for (int k2 = 0; k2 < DPK / 2; k2++) {
    float2 xv = xp[k2];
    float2 av = ap[k2];
    const float* wl = WlT + (2 * k2) * DPK;
    const float* wr = WrT + (2 * k2) * DPK;
#pragma unroll
    for (int o = 0; o < DPK; o++) acc[o] += av.x * wl[o] + xv.x * wr[o];
#pragma unroll
    for (int o = 0; o < DPK; o++) acc[o] += av.y * wl[DPK + o] + xv.y * wr[DPK + o];
  }
  float2* op = (float2*)(out + (size_t)i * DPK);
#pragma unroll
  for (int o2 = 0; o2 < DPK / 2; o2++) {
    float2 w;
    w.x = fmaxf(acc[2 * o2 + 0], 0.f);
    w.y = fmaxf(acc[2 * o2 + 1], 0.f);
    op[o2] = w;
  }
}

// ---------- conv2 + segment-mean pool, K-streaming, output halves, per-thread pool ----------
template <int SPLIT>
__global__ void __launch_bounds__(256, 2) k_sage2_poolT(
    const float* __restrict__ xt1, const float* __restrict__ agg,
    const float* __restrict__ WlT, const float* __restrict__ bl,
    const float* __restrict__ WrT, const int* __restrict__ bstart,
    float* __restrict__ pooled) {
  constexpr int OH = DP2 / 2;
  int b = blockIdx.x / SPLIT;
  int sidx = blockIdx.x - b * SPLIT;
  int obase = blockIdx.y * OH;
  int tid = threadIdx.x;
  int r0 = bstart[b], r1 = bstart[b + 1];
  int len = r1 - r0;
  int per = (len + SPLIT - 1) / SPLIT;
  int s0 = r0 + sidx * per;
  int s1 = min(r1, s0 + per);
  float pool[OH];
#pragma unroll
  for (int o = 0; o < OH; o++) pool[o] = 0.f;
  for (int i = s0 + tid; i < s1; i += 256) {
    float acc[OH];
#pragma unroll
    for (int o = 0; o < OH; o++) acc[o] = bl[obase + o];
    const float2* xp = (const float2*)(xt1 + (size_t)i * DPK);
    const float2* ap = (const float2*)(agg + (size_t)i * DPK);
#pragma unroll 2
    for (int k2 = 0; k2 < DPK / 2; k2++) {
      float2 xv = xp[k2];
      float2 av = ap[k2];
      const float* wl = WlT + (2 * k2) * DP2 + obase;
      const float* wr = WrT + (2 * k2) * DP2 + obase;
#pragma unroll
      for (int o = 0; o < OH; o++) acc[o] += av.x * wl[o] + xv.x * wr[o];
#pragma unroll
      for (int o = 0; o < OH; o++) acc[o] += av.y * wl[DP2 + o] + xv.y * wr[DP2 + o];
    }
#pragma unroll
    for (int o = 0; o < OH; o++) pool[o] += fmaxf(acc[o], 0.f);
  }
#pragma unroll
  for (int o = 0; o < OH; o++) {
#pragma unroll
    for (int off = 1; off < 64; off <<= 1) pool[o] += __shfl_xor(pool[o], off, 64);
  }
  if ((tid & 63) == 0) {
    float* pb = pooled + b * DP2 + obase;
#pragma unroll
    for (int o = 0; o < OH; o++)
      if (pool[o] != 0.f) atomicAdd(&pb[o], pool[o]);
  }
}

// ---------- branch head MLP: mean -> 256 relu -> DOUT (linear) ----------
template <int DIN, int DOUT>
__global__ void K256 k_head(const float* __restrict__ pooled, const int* __restrict__ bstart,
                            const float* __restrict__ W1, const float* __restrict__ b1,
                            const float* __restrict__ W2, const float* __restrict__ b2,
                            float* __restrict__ outv) {
  __shared__ float sx[DIN];
  __shared__ float sh[256];
  int b = blockIdx.x, tid = threadIdx.x;
  float inv = 1.f / fmaxf((float)(bstart[b + 1] - bstart[b]), 1.f);
  for (int f = tid; f < DIN; f += 256) sx[f] = pooled[b * DIN + f] * inv;
  __syncthreads();
  float acc = b1[tid];
#pragma unroll 2
  for (int k = 0; k < DIN; k++) acc += sx[k] * W1[tid * DIN + k];
  sh[tid] = fmaxf(acc, 0.f);
  __syncthreads();
  if (tid < DOUT) {
    float a = b2[tid];
#pragma unroll 4
    for (int k = 0; k < 256; k++) a += sh[k] * W2[tid * 256 + k];
    outv[b * DOUT + tid] = a;
  }
}

// ---------- final: concat -> 1024 relu -> 512 relu -> 1 ----------
__global__ void K256 k_final(const float* __restrict__ molv, const float* __restrict__ prov,
                             const float* __restrict__ W1, const float* __restrict__ b1,
                             const float* __restrict__ W2, const float* __restrict__ b2,
                             const float* __restrict__ W3, const float* __restrict__ b3,
                             float* __restrict__ out) {
  __shared__ float sx[256];
  __shared__ float sh1[1024];
  __shared__ float sh2[512];
  __shared__ float red[4];
  int b = blockIdx.x, tid = threadIdx.x;
  sx[tid] = (tid < 112) ? molv[b * 112 + tid] : prov[b * 144 + (tid - 112)];
  __syncthreads();
  for (int o = tid; o < 1024; o += 256) {
    float a = b1[o];
#pragma unroll 4
    for (int k = 0; k < 256; k++) a += sx[k] * W1[o * 256 + k];
    sh1[o] = fmaxf(a, 0.f);
  }
  __syncthreads();
  for (int o = tid; o < 512; o += 256) {
    float a = b2[o];
#pragma unroll 4
    for (int k = 0; k < 1024; k++) a += sh1[k] * W2[o * 1024 + k];
    sh2[o] = fmaxf(a, 0.f);
  }
  __syncthreads();
  float a = 0.f;
  for (int k = tid; k < 512; k += 256) a += sh2[k] * W3[k];
  for (int off = 32; off > 0; off >>= 1) a += __shfl_down(a, off, 64);
  if ((tid & 63) == 0) red[tid >> 6] = a;
  __syncthreads();
  if (tid == 0) out[b] = red[0] + red[1] + red[2] + red[3] + b3[0];
}

__global__ void k_report(float* out, float v, int n) {
  int i = blockIdx.x * 256 + threadIdx.x;
  if (i < n) out[i] = v;
}

extern "C" void kernel_launch(void* const* d_in, const int* in_sizes, int n_in,
                              void* d_out, int out_size, void* d_ws, size_t ws_size,
                              hipStream_t stream) {
  (void)in_sizes; (void)n_in;
  const float* mol_x = (const float*)d_in[0];
  const int* m_ei = (const int*)d_in[1];
  const int* m_batch = (const int*)d_in[2];
  const float* pro_x = (const float*)d_in[3];
  const int* p_ei = (const int*)d_in[4];
  const int* p_batch = (const int*)d_in[5];
  const float* mol_W1 = (const float*)d_in[6];
  const float* mol_b1 = (const float*)d_in[7];
  const float* mol_W2 = (const float*)d_in[8];
  const float* mol_b2 = (const float*)d_in[9];
  const float* c1_Wl = (const float*)d_in[10];
  const float* c1_bl = (const float*)d_in[11];
  const float* c1_Wr = (const float*)d_in[12];
  const float* c2_Wl = (const float*)d_in[13];
  const float* c2_bl = (const float*)d_in[14];
  const float* c2_Wr = (const float*)d_in[15];
  const float* pro_W1 = (const float*)d_in[16];
  const float* pro_b1 = (const float*)d_in[17];
  const float* pro_W2 = (const float*)d_in[18];
  const float* pro_b2 = (const float*)d_in[19];
  const float* fc1_W = (const float*)d_in[20];
  const float* fc1_b = (const float*)d_in[21];
  const float* fc2_W = (const float*)d_in[22];
  const float* fc2_b = (const float*)d_in[23];
  const float* out_W = (const float*)d_in[24];
  const float* out_b = (const float*)d_in[25];
  float* out = (float*)d_out;
  char* ws = (char*)d_ws;

  const int* m_row = m_ei;       // dst
  const int* m_col = m_ei + EM;  // src
  const int* p_e0 = p_ei;        // src
  const int* p_e1 = p_ei + EP;   // dst

  auto al = [](size_t x) { return (x + 255) & ~(size_t)255; };

  size_t o = 0;
  size_t o_pdeg = o;   o += al((size_t)NP * 4);
  size_t o_pincl = o;  o += al((size_t)NP * 4);
  size_t o_pstart = o; o += al((size_t)NP * 4);
  size_t o_pbsum = o;  o += al(1024);
  size_t o_pcsr = o;   o += al((size_t)EP * 4);
  size_t o_agg = o;    o += al((size_t)NP * DPK * 4);  // also pro binned (25.6MB <= 43.2MB)
  size_t o_xt1 = o;    o += al((size_t)NP * DPK * 4);
  size_t pro_end = o;

  o = 0;
  size_t o_mdeg = o;   o += al((size_t)NM * 4);
  size_t o_mincl = o;  o += al((size_t)NM * 4);
  size_t o_mstart = o; o += al((size_t)NM * 4);
  size_t o_mbsum = o;  o += al(1024);
  size_t o_mcsr = o;   o += al((size_t)EM * 4);
  size_t o_hA = o;     o += al((size_t)NM * DM * 4);  // also mol binned (3.2MB <= 31.2MB)
  size_t o_hB = o;     o += al((size_t)NM * DM * 4);
  size_t mol_end = o;

  size_t tail = al(pro_end > mol_end ? pro_end : mol_end);
  size_t o_poolM = tail; tail += al((size_t)B * DM * 4);
  size_t o_poolP = tail; tail += al((size_t)B * DP2 * 4);
  size_t o_molv = tail;  tail += al((size_t)B * 112 * 4);
  size_t o_prov = tail;  tail += al((size_t)B * 144 * 4);
  size_t o_mbs = tail;   tail += al((size_t)(B + 1) * 4);
  size_t o_pbs = tail;   tail += al((size_t)(B + 1) * 4);
  size_t o_w1l = tail;   tail += al((size_t)DPK * DPK * 4);
  size_t o_w1r = tail;   tail += al((size_t)DPK * DPK * 4);
  size_t o_w2l = tail;   tail += al((size_t)DPK * DP2 * 4);
  size_t o_w2r = tail;   tail += al((size_t)DPK * DP2 * 4);
  size_t o_mbc = tail;   tail += al(512 * 4);
  size_t o_pbc = tail;   tail += al(512 * 4);

  if (ws_size < tail) {
    k_report<<<1, 256, 0, stream>>>(out, (float)(ws_size >> 20), out_size);
    return;
  }

  int* mdeg = (int*)(ws + o_mdeg);
  int* mincl = (int*)(ws + o_mincl);
  int* mstart = (int*)(ws + o_mstart);
  int* mbsum = (int*)(ws + o_mbsum);
  int* mcsr = (int*)(ws + o_mcsr);
  float* hA = (float*)(ws + o_hA);
  float* hB = (float*)(ws + o_hB);
  int* pdeg = (int*)(ws + o_pdeg);
  int* pincl = (int*)(ws + o_pincl);
  int* pstart = (int*)(ws + o_pstart);
  int* pbsum = (int*)(ws + o_pbsum);
  int* pcsr = (int*)(ws + o_pcsr);
  float* agg = (float*)(ws + o_agg);
  float* xt1 = (float*)(ws + o_xt1);
  float* poolM = (float*)(ws + o_poolM);
  float* poolP = (float*)(ws + o_poolP);
  float* molv = (float*)(ws + o_molv);
  float* prov = (float*)(ws + o_prov);
  int* mbs = (int*)(ws + o_mbs);
  int* pbs = (int*)(ws + o_pbs);
  float* w1l = (float*)(ws + o_w1l);
  float* w1r = (float*)(ws + o_w1r);
  float* w2l = (float*)(ws + o_w2l);
  float* w2r = (float*)(ws + o_w2r);
  int* mbc = (int*)(ws + o_mbc);
  int* pbc = (int*)(ws + o_pbc);
  int2* mbinned = (int2*)hA;
  int2* pbinned = (int2*)agg;

  // weight transposes (tiny)
  k_trans<<<(DPK * DPK + 255) / 256, 256, 0, stream>>>(c1_Wl, w1l, DPK, DPK);
  k_trans<<<(DPK * DPK + 255) / 256, 256, 0, stream>>>(c1_Wr, w1r, DPK, DPK);
  k_trans<<<(DP2 * DPK + 255) / 256, 256, 0, stream>>>(c2_Wl, w2l, DP2, DPK);
  k_trans<<<(DP2 * DPK + 255) / 256, 256, 0, stream>>>(c2_Wr, w2r, DP2, DPK);

  // ===== MOL branch =====
  constexpr int SHM = 8;                      // 256 nodes/bucket
  constexpr int NBM = (NM + (1 << SHM) - 1) >> SHM;  // 391
  hipMemsetAsync(mdeg, 0, (size_t)NM * 4, stream);
  k_count4<<<(EM / 4 + 255) / 256, 256, 0, stream>>>((const int4*)m_row, mdeg, EM / 4);
  int nb_m = (NM + 1023) / 1024;
  k_scan1<<<nb_m, 1024, 0, stream>>>(mdeg, mincl, mbsum, NM);
  k_scan2<<<1, 256, 0, stream>>>(mbsum, nb_m);
  k_scan3<<<(NM + 255) / 256, 256, 0, stream>>>(mincl, mdeg, mbsum, mstart, NM);
  k_bcur<SHM><<<(NBM + 255) / 256, 256, 0, stream>>>(mstart, mbc, NM);
  k_bin<SHM><<<(EM + 4095) / 4096, 256, 0, stream>>>(m_col, m_row, mbc, mbinned, EM);
  k_fill2<SHM><<<NBM, 256, 0, stream>>>(mbinned, mstart, mcsr, NM, EM);
  k_bstart<<<(NM + 255) / 256, 256, 0, stream>>>(m_batch, mbs, NM);

  int gb_m = (NM * 64 + 255) / 256;
  k_pool_seg<DM, 3, false><<<B, 256, 0, stream>>>(mol_x, mbs, poolM, 0.05f);
  k_gatherv<DM, false><<<gb_m, 256, 0, stream>>>(mol_x, mstart, mdeg, mcsr, hA, NM, DM);
  k_pool_seg<DM, 3, true><<<B, 256, 0, stream>>>(hA, mbs, poolM, 0.2375f);
  k_gatherv<DM, false><<<gb_m, 256, 0, stream>>>(hA, mstart, mdeg, mcsr, hB, NM, DM);
  k_pool_seg<DM, 3, true><<<B, 256, 0, stream>>>(hB, mbs, poolM, 0.2375f);
  k_gatherv<DM, false><<<gb_m, 256, 0, stream>>>(hB, mstart, mdeg, mcsr, hA, NM, DM);
  k_pool_seg<DM, 3, true><<<B, 256, 0, stream>>>(hA, mbs, poolM, 0.2375f);
  k_gatherv<DM, false><<<gb_m, 256, 0, stream>>>(hA, mstart, mdeg, mcsr, hB, NM, DM);
  k_pool_seg<DM, 3, true><<<B, 256, 0, stream>>>(hB, mbs, poolM, 0.2375f);
  k_head<DM, 112><<<B, 256, 0, stream>>>(poolM, mbs, mol_W1, mol_b1, mol_W2, mol_b2, molv);

  // ===== PRO branch (reuses the mol region) =====
  constexpr int SHP = 9;                      // 512 nodes/bucket
  constexpr int NBP = (NP + (1 << SHP) - 1) >> SHP;  // 391
  hipMemsetAsync(pdeg, 0, (size_t)NP * 4, stream);
  hipMemsetAsync(poolP, 0, (size_t)B * DP2 * 4, stream);
  k_count4<<<(EP / 4 + 255) / 256, 256, 0, stream>>>((const int4*)p_e1, pdeg, EP / 4);
  int nb_p = (NP + 1023) / 1024;
  k_scan1<<<nb_p, 1024, 0, stream>>>(pdeg, pincl, pbsum, NP);
  k_scan2<<<1, 256, 0, stream>>>(pbsum, nb_p);
  k_scan3<<<(NP + 255) / 256, 256, 0, stream>>>(pincl, pdeg, pbsum, pstart, NP);
  k_bcur<SHP><<<(NBP + 255) / 256, 256, 0, stream>>>(pstart, pbc, NP);
  k_bin<SHP><<<(EP + 4095) / 4096, 256, 0, stream>>>(p_e0, p_e1, pbc, pbinned, EP);
  k_fill2<SHP><<<NBP, 256, 0, stream>>>(pbinned, pstart, pcsr, NP, EP);
  k_bstart<<<(NP + 255) / 256, 256, 0, stream>>>(p_batch, pbs, NP);

  int gb_p = (NP * 64 + 255) / 256;
  k_gatherv<DPK, true><<<gb_p, 256, 0, stream>>>(pro_x, pstart, pdeg, pcsr, agg, NP, DPK);
  k_sage_nodeT<<<(NP + 255) / 256, 256, 0, stream>>>(pro_x, agg, w1l, c1_bl, w1r, xt1, NP);
  k_gatherv<DPK, true><<<gb_p, 256, 0, stream>>>(xt1, pstart, pdeg, pcsr, agg, NP, DPK);
  {
    dim3 g2(B * 4, 2);
    k_sage2_poolT<4><<<g2, 256, 0, stream>>>(xt1, agg, w2l, c2_bl, w2r, pbs, poolP);
  }
  k_head<DP2, 144><<<B, 256, 0, stream>>>(poolP, pbs, pro_W1, pro_b1, pro_W2, pro_b2, prov);

  k_final<<<B, 256, 0, stream>>>(molv, prov, fc1_W, fc1_b, fc2_W, fc2_b, out_W, out_b, out);
}